// Round 4
// baseline (241.828 us; speedup 1.0000x reference)
//
#include <hip/hip_runtime.h>
#include <math.h>

#define NS 24

// ws layout: float partials[5][B] rows={sp2,st2,spt,mp,mt} | uint counter (memset to 0 per launch)

#define ROT() { float nr_ = cr*wr - ci*wi, ni_ = cr*wi + ci*wr; cr = nr_; ci = ni_; }

// compile-time table of circle pixels: entries 0..194 in-grid (Voronoi),
// entry 195 = padding pixel (16,24) with label 0. Encoded (yy<<8)|x, yy=y-8.
struct PixTab { unsigned short v[196]; };
__device__ constexpr PixTab make_pix() {
    PixTab t{};
    int n = 0;
    const int w[16] = {0,3,5,6,6,7,7,7,8,7,7,7,6,6,5,3};
    for (int yy = 0; yy < 16; ++yy)
        for (int x = 16 - w[yy]; x <= 16 + w[yy]; ++x)
            if (x < 24) { t.v[n] = (unsigned short)((yy << 8) | x); n = n + 1; }
    t.v[195] = (unsigned short)((8 << 8) | 24);
    return t;
}
__device__ constexpr PixTab PIX = make_pix();

__global__ __launch_bounds__(256)
void loss_main(const float* __restrict__ output, const float* __restrict__ targets,
               float* __restrict__ partials, unsigned int* __restrict__ counter,
               float* __restrict__ out, int B) {
    __shared__ float2 sxy[NS];
    __shared__ float sp[NS];
    __shared__ float tx[NS], ty[NS], ta[NS];
    __shared__ float gx[NS * 32], gy[NS * 32];     // separable gaussian factors (amp in gx)
    __shared__ float2 e2[16 * 33];                 // e = phasor-1, rows y=8..23, stride 33
    __shared__ float gTre[32 * 20], gTim[32 * 20]; // stage-1 out, transposed [l][yy], stride 20
    __shared__ float pm[32 * 40];                  // |pred| fftshifted, stride 40
    __shared__ float redm[4][5];
    __shared__ int is_last;
    __shared__ double fin[4][3];
    __shared__ float finm[4][2];

    const int b = blockIdx.x;
    const int t = threadIdx.x;
    const float* so = output + b * NS * 3;
    const float* tg = targets + b * NS * 3;

    // ---- phase 0: seed/target load + e2 zero-init ----
    if (t < NS) {
        sxy[t] = make_float2(so[3 * t + 0], so[3 * t + 1]);
        sp[t] = so[3 * t + 2];
    }
    if (t >= 64 && t < 64 + NS) {
        int s = t - 64;
        tx[s] = tg[3 * s + 0];
        ty[s] = tg[3 * s + 1];
        ta[s] = tg[3 * s + 2];
    }
    for (int i = t; i < 16 * 33; i += 256) e2[i] = make_float2(0.0f, 0.0f);
    __syncthreads();

    // ---- phase 1a: gaussian factor tables ----
    for (int idx = t; idx < NS * 32; idx += 256) {
        int s = idx >> 5, c = idx & 31;
        float dx = (float)c - tx[s];
        gx[idx] = ta[s] * __expf(dx * dx * (-1.0f / 4.5f));
        float dy = (float)c - ty[s];
        gy[idx] = __expf(dy * dy * (-1.0f / 4.5f));
    }

    // ---- phase 1b: packed Voronoi on the 196 circle pixels (no sqrt: d2 argmin) ----
    if (t < 196) {
        int pv = (int)PIX.v[t];
        int yy = pv >> 8, x = pv & 255;
        float ph;
        if (t < 195) {
            float fi = (float)yy, fj = (float)(x - 8);
            int best = 0;
            float bd = 1e30f;
#pragma unroll
            for (int s = 0; s < NS; ++s) {
                float2 sv = sxy[s];
                float ddx = fi - sv.x, ddy = fj - sv.y;
                float d2 = ddx * ddx + ddy * ddy;
                if (d2 < bd) { bd = d2; best = s; }
            }
            ph = sp[best];
        } else {
            ph = sp[0];   // padding circle pixel (16,24): label 0
        }
        float sv_, cv_;
        __sincosf(6.2831853071795864f * ph, &sv_, &cv_);
        e2[yy * 33 + x] = make_float2(cv_ - 1.0f, sv_);
    }
    __syncthreads();

    // ---- stage 1: row DFT over x=8..24. One chain -> outputs l0 and l0+16 ----
    {
        int yy = t >> 4;       // 0..15
        int l0 = t & 15;       // 0..15
        int m = l0 & 3;        // c(x=8) = (-i)^l0
        float cr = (m == 0) ? 1.f : (m == 2) ? -1.f : 0.f;
        float ci = (m == 1) ? -1.f : (m == 3) ? 1.f : 0.f;
        float wr, wi;
        __sincosf(-(float)l0 * 0.19634954084936207f, &wi, &wr); // e^{-2pi i l0/32}
        float g0r = 0, g0i = 0, g1r = 0, g1i = 0;
        const float2* row = &e2[yy * 33];
#pragma unroll
        for (int xp = 0; xp < 8; ++xp) {
            int x = 8 + 2 * xp;
            float2 a = row[x];
            float tr = a.x * cr - a.y * ci, ti = a.x * ci + a.y * cr;
            g0r += tr; g0i += ti; g1r += tr; g1i += ti;   // x even: (+1)^x
            ROT();
            float2 bb = row[x + 1];
            tr = bb.x * cr - bb.y * ci; ti = bb.x * ci + bb.y * cr;
            g0r += tr; g0i += ti; g1r -= tr; g1i -= ti;   // x odd: (-1)^x
            ROT();
        }
        {   // tail x = 24 (even)
            float2 a = row[24];
            float tr = a.x * cr - a.y * ci, ti = a.x * ci + a.y * cr;
            g0r += tr; g0i += ti; g1r += tr; g1i += ti;
        }
        gTre[l0 * 20 + yy] = g0r;        gTim[l0 * 20 + yy] = g0i;
        gTre[(l0 + 16) * 20 + yy] = g1r; gTim[(l0 + 16) * 20 + yy] = g1i;
    }
    __syncthreads();

    // ---- stage 2: col DFT over y=8..23 (+ analytic (24,16) pixel + DC delta) ----
    {
        int l = t >> 3;      // 0..31
        int k0 = t & 7;      // 0..7 ; k = k0 + 8j
        int m = k0 & 3;      // c(y=8) = (-i)^k0
        float cr = (m == 0) ? 1.f : (m == 2) ? -1.f : 0.f;
        float ci = (m == 1) ? -1.f : (m == 3) ? 1.f : 0.f;
        float wr, wi;
        __sincosf(-(float)k0 * 0.19634954084936207f, &wi, &wr);
        float h0r = 0, h0i = 0, h1r = 0, h1i = 0, h2r = 0, h2i = 0, h3r = 0, h3i = 0;
#pragma unroll
        for (int c4 = 0; c4 < 4; ++c4) {
            float4 gr = *(const float4*)&gTre[l * 20 + 4 * c4];
            float4 gi = *(const float4*)&gTim[l * 20 + 4 * c4];
            float tr, ti;
            tr = gr.x * cr - gi.x * ci; ti = gr.x * ci + gi.x * cr;
            h0r += tr; h0i += ti;
            h1r += tr; h1i += ti;
            h2r += tr; h2i += ti;
            h3r += tr; h3i += ti;
            ROT();
            tr = gr.y * cr - gi.y * ci; ti = gr.y * ci + gi.y * cr;
            h0r += tr; h0i += ti;
            h1r += ti; h1i -= tr;
            h2r -= tr; h2i -= ti;
            h3r -= ti; h3i += tr;
            ROT();
            tr = gr.z * cr - gi.z * ci; ti = gr.z * ci + gi.z * cr;
            h0r += tr; h0i += ti;
            h1r -= tr; h1i -= ti;
            h2r += tr; h2i += ti;
            h3r -= tr; h3i -= ti;
            ROT();
            tr = gr.w * cr - gi.w * ci; ti = gr.w * ci + gi.w * cr;
            h0r += tr; h0i += ti;
            h1r -= ti; h1i += tr;
            h2r -= tr; h2i -= ti;
            h3r += ti; h3i -= tr;
            ROT();
        }
        {   // analytic pixel (24,16): e24 * (-1)^l * i^k0 (same for all j: i^(8j)=1)
            float sv0, cv0;
            __sincosf(6.2831853071795864f * sp[0], &sv0, &cv0);
            float e24r = cv0 - 1.0f, e24i = sv0;
            float ar2 = (m == 0) ? 1.f : (m == 2) ? -1.f : 0.f;  // i^k0
            float ai2 = (m == 1) ? 1.f : (m == 3) ? -1.f : 0.f;
            float sgn = (l & 1) ? -1.f : 1.f;
            float Tr = sgn * (e24r * ar2 - e24i * ai2);
            float Ti = sgn * (e24r * ai2 + e24i * ar2);
            h0r += Tr; h0i += Ti;
            h1r += Tr; h1i += Ti;
            h2r += Tr; h2i += Ti;
            h3r += Tr; h3i += Ti;
        }
        if (t == 0) h0r += 1024.0f;   // FFT(ones) delta at (k,l)=(0,0)
        int v = (l + 16) & 31;
        pm[((k0 + 16) & 31) * 40 + v] = sqrtf(h0r * h0r + h0i * h0i);
        pm[((k0 + 24) & 31) * 40 + v] = sqrtf(h1r * h1r + h1i * h1i);
        pm[(k0)        * 40 + v]      = sqrtf(h2r * h2r + h2i * h2i);
        pm[((k0 + 8))  * 40 + v]      = sqrtf(h3r * h3r + h3i * h3i);
    }
    __syncthreads();

    // ---- target + block reductions: 4 consecutive pixels per thread ----
    float mp = 0.f, mt = 0.f, sp2 = 0.f, st2 = 0.f, spt = 0.f;
    {
        int r = t >> 3;
        int c0 = (t & 7) * 4;
        float4 p4 = *(const float4*)&pm[r * 40 + c0];
        float t0 = 0, t1 = 0, t2 = 0, t3 = 0;
#pragma unroll
        for (int s = 0; s < NS; ++s) {
            float gyv = gy[s * 32 + r];
            float4 g4 = *(const float4*)&gx[s * 32 + c0];
            t0 += gyv * g4.x; t1 += gyv * g4.y;
            t2 += gyv * g4.z; t3 += gyv * g4.w;
        }
        mp = fmaxf(fmaxf(p4.x, p4.y), fmaxf(p4.z, p4.w));
        mt = fmaxf(fmaxf(t0, t1), fmaxf(t2, t3));
        sp2 = p4.x * p4.x + p4.y * p4.y + p4.z * p4.z + p4.w * p4.w;
        st2 = t0 * t0 + t1 * t1 + t2 * t2 + t3 * t3;
        spt = p4.x * t0 + p4.y * t1 + p4.z * t2 + p4.w * t3;
    }

    for (int off = 32; off > 0; off >>= 1) {
        mp  = fmaxf(mp, __shfl_down(mp, off));
        mt  = fmaxf(mt, __shfl_down(mt, off));
        sp2 += __shfl_down(sp2, off);
        st2 += __shfl_down(st2, off);
        spt += __shfl_down(spt, off);
    }
    int wave = t >> 6, lane = t & 63;
    if (lane == 0) {
        redm[wave][0] = sp2; redm[wave][1] = st2; redm[wave][2] = spt;
        redm[wave][3] = mp;  redm[wave][4] = mt;
    }
    __syncthreads();
    if (t == 0) {
        for (int w = 1; w < 4; ++w) {
            sp2 += redm[w][0];
            st2 += redm[w][1];
            spt += redm[w][2];
            mp = fmaxf(mp, redm[w][3]);
            mt = fmaxf(mt, redm[w][4]);
        }
        partials[0 * B + b] = sp2;
        partials[1 * B + b] = st2;
        partials[2 * B + b] = spt;
        partials[3 * B + b] = mp;
        partials[4 * B + b] = mt;
        __threadfence();                               // release partials
        unsigned int old = atomicAdd(counter, 1u);     // device-scope
        is_last = (old == (unsigned int)(gridDim.x - 1)) ? 1 : 0;
    }
    __syncthreads();

    // ---- last finished block reduces all partials (saves 2nd launch) ----
    if (is_last) {
        __threadfence();   // acquire: all other blocks' partials now visible
        double s0 = 0.0, s1 = 0.0, s2 = 0.0;
        float m0 = 0.f, m1 = 0.f;
        for (int i = t; i < B; i += 256) {
            s0 += (double)partials[0 * B + i];
            s1 += (double)partials[1 * B + i];
            s2 += (double)partials[2 * B + i];
            m0 = fmaxf(m0, partials[3 * B + i]);
            m1 = fmaxf(m1, partials[4 * B + i]);
        }
        for (int off = 32; off > 0; off >>= 1) {
            s0 += __shfl_down(s0, off);
            s1 += __shfl_down(s1, off);
            s2 += __shfl_down(s2, off);
            m0 = fmaxf(m0, __shfl_down(m0, off));
            m1 = fmaxf(m1, __shfl_down(m1, off));
        }
        if (lane == 0) {
            fin[wave][0] = s0; fin[wave][1] = s1; fin[wave][2] = s2;
            finm[wave][0] = m0; finm[wave][1] = m1;
        }
        __syncthreads();
        if (t == 0) {
            for (int w = 1; w < 4; ++w) {
                s0 += fin[w][0];
                s1 += fin[w][1];
                s2 += fin[w][2];
                m0 = fmaxf(m0, finm[w][0]);
                m1 = fmaxf(m1, finm[w][1]);
            }
            double Mp = (double)m0, Mt = (double)m1;
            double loss = (s0 * (Mt / Mp) + s1 * (Mp / Mt) - 2.0 * s2) / sqrt(s0 * s1);
            out[0] = (float)loss;
        }
    }
}

extern "C" void kernel_launch(void* const* d_in, const int* in_sizes, int n_in,
                              void* d_out, int out_size, void* d_ws, size_t ws_size,
                              hipStream_t stream) {
    const float* output  = (const float*)d_in[0];
    const float* targets = (const float*)d_in[1];
    int B = in_sizes[0] / (NS * 3);
    float* partials = (float*)d_ws;                                   // 5*B floats
    unsigned int* counter = (unsigned int*)((char*)d_ws + (size_t)5 * B * sizeof(float));

    hipMemsetAsync(counter, 0, sizeof(unsigned int), stream);         // graph-capturable
    loss_main<<<B, 256, 0, stream>>>(output, targets, partials, counter, (float*)d_out, B);
}

// Round 5
// 109.565 us; speedup vs baseline: 2.2072x; 2.2072x over previous
//
#include <hip/hip_runtime.h>
#include <math.h>

#define NS 24

// ws layout (SoA): float partials[5][B] rows = {sp2, st2, spt, mp, mt}

#define ROT() { float nr_ = cr*wr - ci*wi, ni_ = cr*wi + ci*wr; cr = nr_; ci = ni_; }

// compile-time table of circle pixels: entries 0..194 in-grid (Voronoi),
// entry 195 = padding pixel (16,24) with label 0. Encoded (yy<<8)|x, yy=y-8.
struct PixTab { unsigned short v[196]; };
__device__ constexpr PixTab make_pix() {
    PixTab t{};
    int n = 0;
    const int w[16] = {0,3,5,6,6,7,7,7,8,7,7,7,6,6,5,3};
    for (int yy = 0; yy < 16; ++yy)
        for (int x = 16 - w[yy]; x <= 16 + w[yy]; ++x)
            if (x < 24) { t.v[n] = (unsigned short)((yy << 8) | x); n = n + 1; }
    t.v[195] = (unsigned short)((8 << 8) | 24);
    return t;
}
__device__ constexpr PixTab PIX = make_pix();

__global__ __launch_bounds__(256)
void loss_main(const float* __restrict__ output, const float* __restrict__ targets,
               float* __restrict__ partials, int B) {
    __shared__ float2 sxy[NS];
    __shared__ float sp[NS];
    __shared__ float tx[NS], ty[NS], ta[NS];
    __shared__ float2 e24s;                        // phasor(sp[0]) - 1, computed once
    __shared__ float gx[NS * 32], gy[NS * 32];     // separable gaussian factors (amp in gx)
    __shared__ float2 e2[16 * 33];                 // e = phasor-1, rows y=8..23, stride 33
    __shared__ float gTre[32 * 20], gTim[32 * 20]; // stage-1 out, transposed [l][yy], stride 20
    __shared__ float pm[32 * 40];                  // |pred| fftshifted, stride 40
    __shared__ float redm[4][5];

    const int b = blockIdx.x;
    const int t = threadIdx.x;
    const float* so = output + b * NS * 3;
    const float* tg = targets + b * NS * 3;

    // ---- phase 0: seed/target load + e2 zero-init ----
    if (t < NS) {
        sxy[t] = make_float2(so[3 * t + 0], so[3 * t + 1]);
        sp[t] = so[3 * t + 2];
        if (t == 0) {
            float sv0, cv0;
            __sincosf(6.2831853071795864f * sp[0], &sv0, &cv0);
            e24s = make_float2(cv0 - 1.0f, sv0);
        }
    }
    if (t >= 64 && t < 64 + NS) {
        int s = t - 64;
        tx[s] = tg[3 * s + 0];
        ty[s] = tg[3 * s + 1];
        ta[s] = tg[3 * s + 2];
    }
    for (int i = t; i < 16 * 33; i += 256) e2[i] = make_float2(0.0f, 0.0f);
    __syncthreads();

    // ---- phase 1a: gaussian factor tables ----
    for (int idx = t; idx < NS * 32; idx += 256) {
        int s = idx >> 5, c = idx & 31;
        float dx = (float)c - tx[s];
        gx[idx] = ta[s] * __expf(dx * dx * (-1.0f / 4.5f));
        float dy = (float)c - ty[s];
        gy[idx] = __expf(dy * dy * (-1.0f / 4.5f));
    }

    // ---- phase 1b: packed Voronoi on the 196 circle pixels (squared-dist argmin) ----
    if (t < 196) {
        int pv = (int)PIX.v[t];
        int yy = pv >> 8, x = pv & 255;
        float ph;
        if (t < 195) {
            float fi = (float)yy, fj = (float)(x - 8);
            int best = 0;
            float bd = 1e30f;
#pragma unroll
            for (int s = 0; s < NS; ++s) {
                float2 sv = sxy[s];
                float ddx = fi - sv.x, ddy = fj - sv.y;
                float d2 = ddx * ddx + ddy * ddy;
                if (d2 < bd) { bd = d2; best = s; }
            }
            ph = sp[best];
        } else {
            ph = sp[0];   // padding circle pixel (16,24): label 0
        }
        float sv_, cv_;
        __sincosf(6.2831853071795864f * ph, &sv_, &cv_);
        e2[yy * 33 + x] = make_float2(cv_ - 1.0f, sv_);
    }
    __syncthreads();

    // ---- stage 1: row DFT over x=8..24. One chain -> outputs l0 and l0+16 ----
    {
        int yy = t >> 4;       // 0..15
        int l0 = t & 15;       // 0..15
        int m = l0 & 3;        // c(x=8) = (-i)^l0
        float cr = (m == 0) ? 1.f : (m == 2) ? -1.f : 0.f;
        float ci = (m == 1) ? -1.f : (m == 3) ? 1.f : 0.f;
        float wr, wi;
        __sincosf(-(float)l0 * 0.19634954084936207f, &wi, &wr); // e^{-2pi i l0/32}
        float g0r = 0, g0i = 0, g1r = 0, g1i = 0;
        const float2* row = &e2[yy * 33];
#pragma unroll
        for (int xp = 0; xp < 8; ++xp) {
            int x = 8 + 2 * xp;
            float2 a = row[x];
            float tr = a.x * cr - a.y * ci, ti = a.x * ci + a.y * cr;
            g0r += tr; g0i += ti; g1r += tr; g1i += ti;   // x even: (+1)^x
            ROT();
            float2 bb = row[x + 1];
            tr = bb.x * cr - bb.y * ci; ti = bb.x * ci + bb.y * cr;
            g0r += tr; g0i += ti; g1r -= tr; g1i -= ti;   // x odd: (-1)^x
            ROT();
        }
        {   // tail x = 24 (even)
            float2 a = row[24];
            float tr = a.x * cr - a.y * ci, ti = a.x * ci + a.y * cr;
            g0r += tr; g0i += ti; g1r += tr; g1i += ti;
        }
        gTre[l0 * 20 + yy] = g0r;        gTim[l0 * 20 + yy] = g0i;
        gTre[(l0 + 16) * 20 + yy] = g1r; gTim[(l0 + 16) * 20 + yy] = g1i;
    }
    __syncthreads();

    // ---- stage 2: col DFT over y=8..23 (+ analytic (24,16) pixel + DC delta) ----
    {
        int l = t >> 3;      // 0..31
        int k0 = t & 7;      // 0..7 ; k = k0 + 8j
        int m = k0 & 3;      // c(y=8) = (-i)^k0
        float cr = (m == 0) ? 1.f : (m == 2) ? -1.f : 0.f;
        float ci = (m == 1) ? -1.f : (m == 3) ? 1.f : 0.f;
        float wr, wi;
        __sincosf(-(float)k0 * 0.19634954084936207f, &wi, &wr);
        float h0r = 0, h0i = 0, h1r = 0, h1i = 0, h2r = 0, h2i = 0, h3r = 0, h3i = 0;
#pragma unroll
        for (int c4 = 0; c4 < 4; ++c4) {
            float4 gr = *(const float4*)&gTre[l * 20 + 4 * c4];
            float4 gi = *(const float4*)&gTim[l * 20 + 4 * c4];
            float tr, ti;
            tr = gr.x * cr - gi.x * ci; ti = gr.x * ci + gi.x * cr;
            h0r += tr; h0i += ti;
            h1r += tr; h1i += ti;
            h2r += tr; h2i += ti;
            h3r += tr; h3i += ti;
            ROT();
            tr = gr.y * cr - gi.y * ci; ti = gr.y * ci + gi.y * cr;
            h0r += tr; h0i += ti;
            h1r += ti; h1i -= tr;
            h2r -= tr; h2i -= ti;
            h3r -= ti; h3i += tr;
            ROT();
            tr = gr.z * cr - gi.z * ci; ti = gr.z * ci + gi.z * cr;
            h0r += tr; h0i += ti;
            h1r -= tr; h1i -= ti;
            h2r += tr; h2i += ti;
            h3r -= tr; h3i -= ti;
            ROT();
            tr = gr.w * cr - gi.w * ci; ti = gr.w * ci + gi.w * cr;
            h0r += tr; h0i += ti;
            h1r -= ti; h1i += tr;
            h2r -= tr; h2i -= ti;
            h3r += ti; h3i -= tr;
            ROT();
        }
        {   // analytic pixel (24,16): e24 * (-1)^l * i^k0 (same for all j: i^(8j)=1)
            float2 e24 = e24s;
            float ar2 = (m == 0) ? 1.f : (m == 2) ? -1.f : 0.f;  // i^k0
            float ai2 = (m == 1) ? 1.f : (m == 3) ? -1.f : 0.f;
            float sgn = (l & 1) ? -1.f : 1.f;
            float Tr = sgn * (e24.x * ar2 - e24.y * ai2);
            float Ti = sgn * (e24.x * ai2 + e24.y * ar2);
            h0r += Tr; h0i += Ti;
            h1r += Tr; h1i += Ti;
            h2r += Tr; h2i += Ti;
            h3r += Tr; h3i += Ti;
        }
        if (t == 0) h0r += 1024.0f;   // FFT(ones) delta at (k,l)=(0,0)
        int v = (l + 16) & 31;
        pm[((k0 + 16) & 31) * 40 + v] = sqrtf(h0r * h0r + h0i * h0i);
        pm[((k0 + 24) & 31) * 40 + v] = sqrtf(h1r * h1r + h1i * h1i);
        pm[(k0)        * 40 + v]      = sqrtf(h2r * h2r + h2i * h2i);
        pm[((k0 + 8))  * 40 + v]      = sqrtf(h3r * h3r + h3i * h3i);
    }
    __syncthreads();

    // ---- target + block reductions: 4 consecutive pixels per thread ----
    float mp = 0.f, mt = 0.f, sp2 = 0.f, st2 = 0.f, spt = 0.f;
    {
        int r = t >> 3;
        int c0 = (t & 7) * 4;
        float4 p4 = *(const float4*)&pm[r * 40 + c0];
        float t0 = 0, t1 = 0, t2 = 0, t3 = 0;
#pragma unroll
        for (int s = 0; s < NS; ++s) {
            float gyv = gy[s * 32 + r];
            float4 g4 = *(const float4*)&gx[s * 32 + c0];
            t0 += gyv * g4.x; t1 += gyv * g4.y;
            t2 += gyv * g4.z; t3 += gyv * g4.w;
        }
        mp = fmaxf(fmaxf(p4.x, p4.y), fmaxf(p4.z, p4.w));
        mt = fmaxf(fmaxf(t0, t1), fmaxf(t2, t3));
        sp2 = p4.x * p4.x + p4.y * p4.y + p4.z * p4.z + p4.w * p4.w;
        st2 = t0 * t0 + t1 * t1 + t2 * t2 + t3 * t3;
        spt = p4.x * t0 + p4.y * t1 + p4.z * t2 + p4.w * t3;
    }

    for (int off = 32; off > 0; off >>= 1) {
        mp  = fmaxf(mp, __shfl_down(mp, off));
        mt  = fmaxf(mt, __shfl_down(mt, off));
        sp2 += __shfl_down(sp2, off);
        st2 += __shfl_down(st2, off);
        spt += __shfl_down(spt, off);
    }
    int wave = t >> 6, lane = t & 63;
    if (lane == 0) {
        redm[wave][0] = sp2; redm[wave][1] = st2; redm[wave][2] = spt;
        redm[wave][3] = mp;  redm[wave][4] = mt;
    }
    __syncthreads();
    if (t == 0) {
        for (int w = 1; w < 4; ++w) {
            sp2 += redm[w][0];
            st2 += redm[w][1];
            spt += redm[w][2];
            mp = fmaxf(mp, redm[w][3]);
            mt = fmaxf(mt, redm[w][4]);
        }
        // plain stores -- NO atomics, NO fences. Round-4 lesson: one contended
        // same-line device atomic per block = ~12ns each = ~98us serialized.
        partials[0 * B + b] = sp2;
        partials[1 * B + b] = st2;
        partials[2 * B + b] = spt;
        partials[3 * B + b] = mp;
        partials[4 * B + b] = mt;
    }
}

__global__ __launch_bounds__(1024)
void finalize_loss(const float* __restrict__ partials, float* __restrict__ out, int B) {
    __shared__ double reds[16][3];
    __shared__ float redx[16][2];
    const int t = threadIdx.x;
    double sp2 = 0.0, st2 = 0.0, spt = 0.0;
    float mp = 0.f, mt = 0.f;
    for (int i = t; i < B; i += 1024) {
        sp2 += (double)partials[0 * B + i];
        st2 += (double)partials[1 * B + i];
        spt += (double)partials[2 * B + i];
        mp = fmaxf(mp, partials[3 * B + i]);
        mt = fmaxf(mt, partials[4 * B + i]);
    }
    for (int off = 32; off > 0; off >>= 1) {
        sp2 += __shfl_down(sp2, off);
        st2 += __shfl_down(st2, off);
        spt += __shfl_down(spt, off);
        mp = fmaxf(mp, __shfl_down(mp, off));
        mt = fmaxf(mt, __shfl_down(mt, off));
    }
    int wave = t >> 6, lane = t & 63;
    if (lane == 0) {
        reds[wave][0] = sp2; reds[wave][1] = st2; reds[wave][2] = spt;
        redx[wave][0] = mp;  redx[wave][1] = mt;
    }
    __syncthreads();
    if (t == 0) {
        for (int w = 1; w < 16; ++w) {
            sp2 += reds[w][0];
            st2 += reds[w][1];
            spt += reds[w][2];
            mp = fmaxf(mp, redx[w][0]);
            mt = fmaxf(mt, redx[w][1]);
        }
        double Mp = (double)mp, Mt = (double)mt;
        double loss = (sp2 * (Mt / Mp) + st2 * (Mp / Mt) - 2.0 * spt) / sqrt(sp2 * st2);
        out[0] = (float)loss;
    }
}

extern "C" void kernel_launch(void* const* d_in, const int* in_sizes, int n_in,
                              void* d_out, int out_size, void* d_ws, size_t ws_size,
                              hipStream_t stream) {
    const float* output  = (const float*)d_in[0];
    const float* targets = (const float*)d_in[1];
    int B = in_sizes[0] / (NS * 3);
    float* partials = (float*)d_ws;     // 5*B floats

    loss_main<<<B, 256, 0, stream>>>(output, targets, partials, B);
    finalize_loss<<<1, 1024, 0, stream>>>(partials, (float*)d_out, B);
}

// Round 6
// 107.927 us; speedup vs baseline: 2.2407x; 1.0152x over previous
//
#include <hip/hip_runtime.h>
#include <math.h>

#define NS 24

typedef float v2f __attribute__((ext_vector_type(2)));
typedef float v4f __attribute__((ext_vector_type(4)));

// ws layout (SoA): float partials[5][B] rows = {sp2, st2, spt, mp, mt}

// compile-time table of circle pixels: entries 0..194 in-grid (Voronoi),
// entry 195 = padding pixel (16,24) with label 0. Encoded (yy<<8)|x, yy=y-8.
struct PixTab { unsigned short v[196]; };
__device__ constexpr PixTab make_pix() {
    PixTab t{};
    int n = 0;
    const int w[16] = {0,3,5,6,6,7,7,7,8,7,7,7,6,6,5,3};
    for (int yy = 0; yy < 16; ++yy)
        for (int x = 16 - w[yy]; x <= 16 + w[yy]; ++x)
            if (x < 24) { t.v[n] = (unsigned short)((yy << 8) | x); n = n + 1; }
    t.v[195] = (unsigned short)((8 << 8) | 24);
    return t;
}
__device__ constexpr PixTab PIX = make_pix();

// packed complex mul: (re,im) pair t = e * w, with w4 = (wr, wi, -wi, wr)
#define CMUL(e_, w4_) \
    __builtin_elementwise_fma((v2f){(e_).y, (e_).y}, (v2f){(w4_).z, (w4_).w}, \
                              (v2f){(e_).x, (e_).x} * (v2f){(w4_).x, (w4_).y})

__global__ __launch_bounds__(256)
void loss_main(const float* __restrict__ output, const float* __restrict__ targets,
               float* __restrict__ partials, int B) {
    __shared__ float2 sxy[NS];
    __shared__ float sp[NS];
    __shared__ float tx[NS], ty[NS], ta[NS];
    __shared__ float2 e24s;                          // phasor(sp[0]) - 1
    __shared__ __align__(16) float gx[NS * 32], gy[NS * 32]; // gaussian factors (amp in gx)
    __shared__ __align__(16) float e2f[16 * 33 * 2]; // e = phasor-1, rows y=8..23, stride 33 cplx
    __shared__ __align__(16) float tw2f[16 * 8 * 4]; // stage-2 twiddles [yp][k0] float4
    __shared__ __align__(16) float gT2f[32 * 36];    // stage-1 out, [l][yp] cplx, stride 36 fl
    __shared__ __align__(16) char uA[5120];          // union: tw1 (4352B) then pm (5120B)
    __shared__ float redm[4][5];

    float* tw1f = (float*)uA;  // stage-1 twiddles [xp][l0] float4 -- dead after stage 1
    float* pmf  = (float*)uA;  // |pred| fftshifted, stride 40 -- written in stage 2

    const int b = blockIdx.x;
    const int t = threadIdx.x;
    const float* so = output + b * NS * 3;
    const float* tg = targets + b * NS * 3;

    // ---- phase 0: seed/target load + e2 zero-init ----
    if (t < NS) {
        sxy[t] = make_float2(so[3 * t + 0], so[3 * t + 1]);
        sp[t] = so[3 * t + 2];
        if (t == 0) {
            float sv0, cv0;
            __sincosf(6.2831853071795864f * sp[0], &sv0, &cv0);
            e24s = make_float2(cv0 - 1.0f, sv0);
        }
    }
    if (t >= 64 && t < 64 + NS) {
        int s = t - 64;
        tx[s] = tg[3 * s + 0];
        ty[s] = tg[3 * s + 1];
        ta[s] = tg[3 * s + 2];
    }
    for (int i = t; i < 16 * 33; i += 256) *(v2f*)&e2f[i * 2] = (v2f){0.f, 0.f};
    __syncthreads();

    // ---- phase 1a: gaussian factor tables ----
    for (int idx = t; idx < NS * 32; idx += 256) {
        int s = idx >> 5, c = idx & 31;
        float dx = (float)c - tx[s];
        gx[idx] = ta[s] * __expf(dx * dx * (-1.0f / 4.5f));
        float dy = (float)c - ty[s];
        gy[idx] = __expf(dy * dy * (-1.0f / 4.5f));
    }

    // ---- phase 1t: twiddle tables, exact integer phase (f*x mod 32) ----
    // tw1[xp][l0] = e^{-2pi i l0 (xp+8)/32}, xp in [0,17), l0 in [0,16)
    // tw2[yp][k0] = e^{-2pi i k0 (yp+8)/32}, yp in [0,16), k0 in [0,8)
    for (int i = t; i < 400; i += 256) {
        int p;
        float* dst;
        if (i < 272) {
            int xp = i >> 4, l0 = i & 15;
            p = (l0 * (xp + 8)) & 31;
            dst = &tw1f[i * 4];
        } else {
            int j = i - 272;
            int yp = j >> 3, k0 = j & 7;
            p = (k0 * (yp + 8)) & 31;
            dst = &tw2f[j * 4];
        }
        float si, co;
        __sincosf(-(float)p * 0.19634954084936207f, &si, &co);
        dst[0] = co; dst[1] = si; dst[2] = -si; dst[3] = co;
    }

    // ---- phase 1b: packed Voronoi on the 196 circle pixels (squared-dist argmin) ----
    if (t < 196) {
        int pv = (int)PIX.v[t];
        int yy = pv >> 8, x = pv & 255;
        float ph;
        if (t < 195) {
            float fi = (float)yy, fj = (float)(x - 8);
            int best = 0;
            float bd = 1e30f;
#pragma unroll
            for (int s = 0; s < NS; ++s) {
                float2 sv = sxy[s];
                float ddx = fi - sv.x, ddy = fj - sv.y;
                float d2 = ddx * ddx + ddy * ddy;
                if (d2 < bd) { bd = d2; best = s; }
            }
            ph = sp[best];
        } else {
            ph = sp[0];   // padding circle pixel (16,24): label 0
        }
        float sv_, cv_;
        __sincosf(6.2831853071795864f * ph, &sv_, &cv_);
        *(v2f*)&e2f[(yy * 33 + x) * 2] = (v2f){cv_ - 1.0f, sv_};
    }
    __syncthreads();

    // ---- stage 1: row DFT over x=8..24, packed complex MACs, table twiddles ----
    // thread (yy = t>>4, l0 = t&15) -> outputs l0 (g0) and l0+16 (g1, (-1)^x weights)
    {
        int yy = t >> 4, l0 = t & 15;
        v2f g0 = {0.f, 0.f}, g1 = {0.f, 0.f};
        const int rb = (yy * 33 + 8) * 2;
#pragma unroll
        for (int xp = 0; xp < 17; ++xp) {
            v2f e = *(const v2f*)&e2f[rb + xp * 2];
            v4f w4 = *(const v4f*)&tw1f[(xp * 16 + l0) * 4];
            v2f tt = CMUL(e, w4);
            g0 += tt;
            if (xp & 1) g1 -= tt; else g1 += tt;   // parity(x) = parity(xp)
        }
        *(v2f*)&gT2f[l0 * 36 + yy * 2] = g0;
        *(v2f*)&gT2f[(l0 + 16) * 36 + yy * 2] = g1;
    }
    __syncthreads();

    // ---- stage 2: col DFT over y=8..23; 4 outputs k=k0+8j via (-i)^(j*yp) swizzles ----
    {
        int l = t >> 3, k0 = t & 7;
        v2f h0 = {0,0}, h1 = {0,0}, h2 = {0,0}, h3 = {0,0};
#pragma unroll
        for (int q = 0; q < 4; ++q) {
            v4f ga = *(const v4f*)&gT2f[l * 36 + q * 8];       // yp = 4q, 4q+1
            v4f gb = *(const v4f*)&gT2f[l * 36 + q * 8 + 4];   // yp = 4q+2, 4q+3
            {   // yp = 4q : class 0 (all +t)
                v4f w4 = *(const v4f*)&tw2f[((4 * q) * 8 + k0) * 4];
                v2f ge = {ga.x, ga.y};
                v2f tt = CMUL(ge, w4);
                h0 += tt; h1 += tt; h2 += tt; h3 += tt;
            }
            {   // yp = 4q+1 : class 1 (j=1: t*(-i)=(t.y,-t.x); j=2: -t; j=3: -(t.y,-t.x))
                v4f w4 = *(const v4f*)&tw2f[((4 * q + 1) * 8 + k0) * 4];
                v2f ge = {ga.z, ga.w};
                v2f tt = CMUL(ge, w4);
                v2f u = {tt.y, -tt.x};
                h0 += tt; h1 += u; h2 -= tt; h3 -= u;
            }
            {   // yp = 4q+2 : class 2 (alternating sign)
                v4f w4 = *(const v4f*)&tw2f[((4 * q + 2) * 8 + k0) * 4];
                v2f ge = {gb.x, gb.y};
                v2f tt = CMUL(ge, w4);
                h0 += tt; h1 -= tt; h2 += tt; h3 -= tt;
            }
            {   // yp = 4q+3 : class 3
                v4f w4 = *(const v4f*)&tw2f[((4 * q + 3) * 8 + k0) * 4];
                v2f ge = {gb.z, gb.w};
                v2f tt = CMUL(ge, w4);
                v2f u = {tt.y, -tt.x};
                h0 += tt; h1 -= u; h2 -= tt; h3 += u;
            }
        }
        {   // analytic pixel (24,16): e24 * (-1)^l * i^k0  (same for all j: i^(8j)=1)
            float2 e24 = e24s;
            int m = k0 & 3;
            float ar2 = (m == 0) ? 1.f : (m == 2) ? -1.f : 0.f;  // i^k0
            float ai2 = (m == 1) ? 1.f : (m == 3) ? -1.f : 0.f;
            float sgn = (l & 1) ? -1.f : 1.f;
            v2f T = {sgn * (e24.x * ar2 - e24.y * ai2),
                     sgn * (e24.x * ai2 + e24.y * ar2)};
            h0 += T; h1 += T; h2 += T; h3 += T;
        }
        if (t == 0) h0.x += 1024.0f;   // FFT(ones) delta at (k,l)=(0,0)
        int v = (l + 16) & 31;
        v2f q0 = h0 * h0, q1 = h1 * h1, q2 = h2 * h2, q3 = h3 * h3;
        pmf[((k0 + 16) & 31) * 40 + v] = sqrtf(q0.x + q0.y);
        pmf[((k0 + 24) & 31) * 40 + v] = sqrtf(q1.x + q1.y);
        pmf[(k0)        * 40 + v]      = sqrtf(q2.x + q2.y);
        pmf[(k0 + 8)    * 40 + v]      = sqrtf(q3.x + q3.y);
    }
    __syncthreads();

    // ---- target + block reductions: 4 consecutive pixels per thread, packed FMAs ----
    float mp, mt, sp2, st2, spt;
    {
        int r = t >> 3;
        int c0 = (t & 7) * 4;
        v4f p4 = *(const v4f*)&pmf[r * 40 + c0];
        v2f t01 = {0.f, 0.f}, t23 = {0.f, 0.f};
#pragma unroll
        for (int s = 0; s < NS; ++s) {
            float gyv = gy[s * 32 + r];
            v4f g4 = *(const v4f*)&gx[s * 32 + c0];
            v2f gv = {gyv, gyv};
            t01 = __builtin_elementwise_fma(gv, (v2f){g4.x, g4.y}, t01);
            t23 = __builtin_elementwise_fma(gv, (v2f){g4.z, g4.w}, t23);
        }
        v2f p01 = {p4.x, p4.y}, p23 = {p4.z, p4.w};
        v2f s2v = __builtin_elementwise_fma(p23, p23, p01 * p01);
        v2f t2v = __builtin_elementwise_fma(t23, t23, t01 * t01);
        v2f ptv = __builtin_elementwise_fma(p23, t23, p01 * t01);
        sp2 = s2v.x + s2v.y;
        st2 = t2v.x + t2v.y;
        spt = ptv.x + ptv.y;
        mp = fmaxf(fmaxf(p4.x, p4.y), fmaxf(p4.z, p4.w));
        mt = fmaxf(fmaxf(t01.x, t01.y), fmaxf(t23.x, t23.y));
    }

    for (int off = 32; off > 0; off >>= 1) {
        mp  = fmaxf(mp, __shfl_down(mp, off));
        mt  = fmaxf(mt, __shfl_down(mt, off));
        sp2 += __shfl_down(sp2, off);
        st2 += __shfl_down(st2, off);
        spt += __shfl_down(spt, off);
    }
    int wave = t >> 6, lane = t & 63;
    if (lane == 0) {
        redm[wave][0] = sp2; redm[wave][1] = st2; redm[wave][2] = spt;
        redm[wave][3] = mp;  redm[wave][4] = mt;
    }
    __syncthreads();
    if (t == 0) {
        for (int w = 1; w < 4; ++w) {
            sp2 += redm[w][0];
            st2 += redm[w][1];
            spt += redm[w][2];
            mp = fmaxf(mp, redm[w][3]);
            mt = fmaxf(mt, redm[w][4]);
        }
        // plain stores -- NO atomics, NO fences (round-4 lesson: contended
        // same-line device atomics serialize at ~12ns each).
        partials[0 * B + b] = sp2;
        partials[1 * B + b] = st2;
        partials[2 * B + b] = spt;
        partials[3 * B + b] = mp;
        partials[4 * B + b] = mt;
    }
}

__global__ __launch_bounds__(1024)
void finalize_loss(const float* __restrict__ partials, float* __restrict__ out, int B) {
    __shared__ double reds[16][3];
    __shared__ float redx[16][2];
    const int t = threadIdx.x;
    double sp2 = 0.0, st2 = 0.0, spt = 0.0;
    float mp = 0.f, mt = 0.f;
    for (int i = t; i < B; i += 1024) {
        sp2 += (double)partials[0 * B + i];
        st2 += (double)partials[1 * B + i];
        spt += (double)partials[2 * B + i];
        mp = fmaxf(mp, partials[3 * B + i]);
        mt = fmaxf(mt, partials[4 * B + i]);
    }
    for (int off = 32; off > 0; off >>= 1) {
        sp2 += __shfl_down(sp2, off);
        st2 += __shfl_down(st2, off);
        spt += __shfl_down(spt, off);
        mp = fmaxf(mp, __shfl_down(mp, off));
        mt = fmaxf(mt, __shfl_down(mt, off));
    }
    int wave = t >> 6, lane = t & 63;
    if (lane == 0) {
        reds[wave][0] = sp2; reds[wave][1] = st2; reds[wave][2] = spt;
        redx[wave][0] = mp;  redx[wave][1] = mt;
    }
    __syncthreads();
    if (t == 0) {
        for (int w = 1; w < 16; ++w) {
            sp2 += reds[w][0];
            st2 += reds[w][1];
            spt += reds[w][2];
            mp = fmaxf(mp, redx[w][0]);
            mt = fmaxf(mt, redx[w][1]);
        }
        double Mp = (double)mp, Mt = (double)mt;
        double loss = (sp2 * (Mt / Mp) + st2 * (Mp / Mt) - 2.0 * spt) / sqrt(sp2 * st2);
        out[0] = (float)loss;
    }
}

extern "C" void kernel_launch(void* const* d_in, const int* in_sizes, int n_in,
                              void* d_out, int out_size, void* d_ws, size_t ws_size,
                              hipStream_t stream) {
    const float* output  = (const float*)d_in[0];
    const float* targets = (const float*)d_in[1];
    int B = in_sizes[0] / (NS * 3);
    float* partials = (float*)d_ws;     // 5*B floats

    loss_main<<<B, 256, 0, stream>>>(output, targets, partials, B);
    finalize_loss<<<1, 1024, 0, stream>>>(partials, (float*)d_out, B);
}

// Round 7
// 105.306 us; speedup vs baseline: 2.2964x; 1.0249x over previous
//
#include <hip/hip_runtime.h>
#include <math.h>

#define NS 24

typedef float v2f __attribute__((ext_vector_type(2)));
typedef float v4f __attribute__((ext_vector_type(4)));

// ws layout (SoA): float partials[5][B] rows = {sp2, st2, spt, mp, mt}

// compile-time table of circle pixels: entries 0..194 in-grid (Voronoi),
// entry 195 = padding pixel (16,24) with label 0. Encoded (yy<<8)|x, yy=y-8.
struct PixTab { unsigned short v[196]; };
__device__ constexpr PixTab make_pix() {
    PixTab t{};
    int n = 0;
    const int w[16] = {0,3,5,6,6,7,7,7,8,7,7,7,6,6,5,3};
    for (int yy = 0; yy < 16; ++yy)
        for (int x = 16 - w[yy]; x <= 16 + w[yy]; ++x)
            if (x < 24) { t.v[n] = (unsigned short)((yy << 8) | x); n = n + 1; }
    t.v[195] = (unsigned short)((8 << 8) | 24);
    return t;
}
__device__ constexpr PixTab PIX = make_pix();

// packed complex mul with w = (c, s):
//   t.re = e.x*c - e.y*s ; t.im = e.x*s + e.y*c
// neg+swizzle should fold into VOP3P op_sel/neg modifiers.
static __device__ __forceinline__ v2f cmul(v2f e, v2f w) {
    v2f m = (v2f){e.y, e.y} * (v2f){w.y, w.x};
    return __builtin_elementwise_fma((v2f){e.x, e.x}, w, (v2f){-m.x, m.y});
}

__global__ __launch_bounds__(256)
void loss_main(const float* __restrict__ output, const float* __restrict__ targets,
               float* __restrict__ partials, int B) {
    __shared__ float2 sxy[NS];
    __shared__ float sp[NS];
    __shared__ float tx[NS], ty[NS], ta[NS];
    __shared__ float2 e24s;                           // phasor(sp[0]) - 1
    __shared__ __align__(16) float gx[NS * 32];       // gaussian x-factors (amp folded in)
    __shared__ __align__(16) float gyT[32 * 36];      // gaussian y-factors, [r][s], stride 36
    __shared__ __align__(16) float e2f[16 * 34 * 2];  // e = phasor-1, rows y=8..23, stride 34 cplx
    __shared__ __align__(16) float tw2f[8 * 36];      // stage-2 twiddles [k0][yp] (c,s), stride 18 cplx
    __shared__ __align__(16) float gT2f[32 * 36];     // stage-1 out [l][yp] cplx, stride 18 cplx
    __shared__ __align__(16) char uA[5120];           // union: tw1v (2304B) then pm (5120B)
    __shared__ float redm[4][5];

    float* tw1f = (float*)uA;  // stage-1 twiddles [l0][xp] (c,s), stride 18 cplx -- dead after stage 1
    float* pmf  = (float*)uA;  // |pred| fftshifted, stride 40 -- written in stage 2

    const int b = blockIdx.x;
    const int t = threadIdx.x;
    const float* so = output + b * NS * 3;
    const float* tg = targets + b * NS * 3;

    // ---- phase 0: seed/target load + e2 zero-init ----
    if (t < NS) {
        sxy[t] = make_float2(so[3 * t + 0], so[3 * t + 1]);
        sp[t] = so[3 * t + 2];
        if (t == 0) {
            float sv0, cv0;
            __sincosf(6.2831853071795864f * sp[0], &sv0, &cv0);
            e24s = make_float2(cv0 - 1.0f, sv0);
        }
    }
    if (t >= 64 && t < 64 + NS) {
        int s = t - 64;
        tx[s] = tg[3 * s + 0];
        ty[s] = tg[3 * s + 1];
        ta[s] = tg[3 * s + 2];
    }
    for (int i = t; i < 16 * 34; i += 256) *(v2f*)&e2f[i * 2] = (v2f){0.f, 0.f};
    __syncthreads();

    // ---- phase 1a: gaussian factor tables ----
    for (int idx = t; idx < NS * 32; idx += 256) {
        int s = idx >> 5, c = idx & 31;
        float dx = (float)c - tx[s];
        gx[idx] = ta[s] * __expf(dx * dx * (-1.0f / 4.5f));
    }
    for (int idx = t; idx < 32 * 32; idx += 256) {
        int r = idx >> 5, s = idx & 31;
        if (s < NS) {
            float dy = (float)r - ty[s];
            gyT[r * 36 + s] = __expf(dy * dy * (-1.0f / 4.5f));
        }
    }

    // ---- phase 1t: twiddle tables, exact integer phase (f*x mod 32), (c,s) format ----
    // tw1[l0][xp] = e^{-2pi i l0 (xp+8)/32}, l0 in [0,16), xp in [0,17), stride 18 cplx
    for (int i = t; i < 16 * 18; i += 256) {
        int l0 = i / 18, xp = i - l0 * 18;
        if (xp < 17) {
            int p = (l0 * (xp + 8)) & 31;
            float si, co;
            __sincosf(-(float)p * 0.19634954084936207f, &si, &co);
            *(v2f*)&tw1f[i * 2] = (v2f){co, si};
        }
    }
    // tw2[k0][yp] = e^{-2pi i k0 (yp+8)/32}, k0 in [0,8), yp in [0,16), stride 18 cplx
    if (t < 128) {
        int k0 = t >> 4, yp = t & 15;
        int p = (k0 * (yp + 8)) & 31;
        float si, co;
        __sincosf(-(float)p * 0.19634954084936207f, &si, &co);
        *(v2f*)&tw2f[k0 * 36 + yp * 2] = (v2f){co, si};
    }

    // ---- phase 1b: packed Voronoi on the 196 circle pixels (squared-dist argmin) ----
    if (t < 196) {
        int pv = (int)PIX.v[t];
        int yy = pv >> 8, x = pv & 255;
        float ph;
        if (t < 195) {
            float fi = (float)yy, fj = (float)(x - 8);
            int best = 0;
            float bd = 1e30f;
#pragma unroll
            for (int s = 0; s < NS; ++s) {
                float2 sv = sxy[s];
                float ddx = fi - sv.x, ddy = fj - sv.y;
                float d2 = ddx * ddx + ddy * ddy;
                if (d2 < bd) { bd = d2; best = s; }
            }
            ph = sp[best];
        } else {
            ph = sp[0];   // padding circle pixel (16,24): label 0
        }
        float sv_, cv_;
        __sincosf(6.2831853071795864f * ph, &sv_, &cv_);
        *(v2f*)&e2f[(yy * 34 + x) * 2] = (v2f){cv_ - 1.0f, sv_};
    }
    __syncthreads();

    // ---- stage 1: row DFT over x=8..24, wide LDS loads, packed complex MACs ----
    // thread (yy = t>>4, l0 = t&15) -> outputs l0 (g0) and l0+16 (g1, (-1)^x weights)
    {
        int yy = t >> 4, l0 = t & 15;
        const float* row = &e2f[(yy * 34 + 8) * 2];
        const float* twr = &tw1f[l0 * 36];
        v2f g0 = {0.f, 0.f}, g1 = {0.f, 0.f};
#pragma unroll
        for (int q = 0; q < 8; ++q) {
            v4f e4 = *(const v4f*)&row[q * 4];   // complex x=8+2q (even), x=9+2q (odd)
            v4f w4 = *(const v4f*)&twr[q * 4];
            v2f ca = cmul((v2f){e4.x, e4.y}, (v2f){w4.x, w4.y});
            v2f cb = cmul((v2f){e4.z, e4.w}, (v2f){w4.z, w4.w});
            g0 += ca + cb;
            g1 += ca - cb;
        }
        {   // tail x = 24 (xp=16, even)
            v2f e16 = *(const v2f*)&row[32];
            v2f w16 = *(const v2f*)&twr[32];
            v2f c16 = cmul(e16, w16);
            g0 += c16; g1 += c16;
        }
        *(v2f*)&gT2f[l0 * 36 + yy * 2] = g0;
        *(v2f*)&gT2f[(l0 + 16) * 36 + yy * 2] = g1;
    }
    __syncthreads();

    // ---- stage 2: col DFT over y=8..23; 4 outputs k=k0+8j via radix-4 combine ----
    {
        int l = t >> 3, k0 = t & 7;
        const float* gTr = &gT2f[l * 36];
        const float* twr = &tw2f[k0 * 36];
        v2f h0 = {0,0}, h1 = {0,0}, h2 = {0,0}, h3 = {0,0};
#pragma unroll
        for (int q = 0; q < 4; ++q) {
            v4f ga = *(const v4f*)&gTr[q * 8];       // yp = 4q, 4q+1
            v4f gb = *(const v4f*)&gTr[q * 8 + 4];   // yp = 4q+2, 4q+3
            v4f wa = *(const v4f*)&twr[q * 8];
            v4f wb = *(const v4f*)&twr[q * 8 + 4];
            v2f t0 = cmul((v2f){ga.x, ga.y}, (v2f){wa.x, wa.y});  // class 0
            v2f t1 = cmul((v2f){ga.z, ga.w}, (v2f){wa.z, wa.w});  // class 1
            v2f t2 = cmul((v2f){gb.x, gb.y}, (v2f){wb.x, wb.y});  // class 2
            v2f t3 = cmul((v2f){gb.z, gb.w}, (v2f){wb.z, wb.w});  // class 3
            v2f a = t0 + t2, bb = t0 - t2;
            v2f c = t1 + t3, d = t1 - t3;
            v2f du = {d.y, -d.x};                                 // d * (-i)
            h0 += a + c;
            h1 += bb + du;
            h2 += a - c;
            h3 += bb - du;
        }
        {   // analytic pixel (24,16): e24 * (-1)^l * i^k0  (same for all j: i^(8j)=1)
            float2 e24 = e24s;
            int m = k0 & 3;
            float ar2 = (m == 0) ? 1.f : (m == 2) ? -1.f : 0.f;  // i^k0
            float ai2 = (m == 1) ? 1.f : (m == 3) ? -1.f : 0.f;
            float sgn = (l & 1) ? -1.f : 1.f;
            v2f T = {sgn * (e24.x * ar2 - e24.y * ai2),
                     sgn * (e24.x * ai2 + e24.y * ar2)};
            h0 += T; h1 += T; h2 += T; h3 += T;
        }
        if (t == 0) h0.x += 1024.0f;   // FFT(ones) delta at (k,l)=(0,0)
        int v = (l + 16) & 31;
        v2f q0 = h0 * h0, q1 = h1 * h1, q2 = h2 * h2, q3 = h3 * h3;
        pmf[((k0 + 16) & 31) * 40 + v] = sqrtf(q0.x + q0.y);
        pmf[((k0 + 24) & 31) * 40 + v] = sqrtf(q1.x + q1.y);
        pmf[(k0)        * 40 + v]      = sqrtf(q2.x + q2.y);
        pmf[(k0 + 8)    * 40 + v]      = sqrtf(q3.x + q3.y);
    }
    __syncthreads();

    // ---- target + block reductions: 4 consecutive pixels per thread, packed FMAs ----
    float mp, mt, sp2, st2, spt;
    {
        int r = t >> 3;
        int c0 = (t & 7) * 4;
        v4f p4 = *(const v4f*)&pmf[r * 40 + c0];
        v2f t01 = {0.f, 0.f}, t23 = {0.f, 0.f};
#pragma unroll
        for (int q = 0; q < 6; ++q) {
            v4f gy4 = *(const v4f*)&gyT[r * 36 + q * 4];   // gy for seeds 4q..4q+3
#pragma unroll
            for (int j = 0; j < 4; ++j) {
                int s = 4 * q + j;
                v4f g4 = *(const v4f*)&gx[s * 32 + c0];
                float gyv = (j == 0) ? gy4.x : (j == 1) ? gy4.y : (j == 2) ? gy4.z : gy4.w;
                v2f gv = {gyv, gyv};
                t01 = __builtin_elementwise_fma(gv, (v2f){g4.x, g4.y}, t01);
                t23 = __builtin_elementwise_fma(gv, (v2f){g4.z, g4.w}, t23);
            }
        }
        v2f p01 = {p4.x, p4.y}, p23 = {p4.z, p4.w};
        v2f s2v = __builtin_elementwise_fma(p23, p23, p01 * p01);
        v2f t2v = __builtin_elementwise_fma(t23, t23, t01 * t01);
        v2f ptv = __builtin_elementwise_fma(p23, t23, p01 * t01);
        sp2 = s2v.x + s2v.y;
        st2 = t2v.x + t2v.y;
        spt = ptv.x + ptv.y;
        mp = fmaxf(fmaxf(p4.x, p4.y), fmaxf(p4.z, p4.w));
        mt = fmaxf(fmaxf(t01.x, t01.y), fmaxf(t23.x, t23.y));
    }

    for (int off = 32; off > 0; off >>= 1) {
        mp  = fmaxf(mp, __shfl_down(mp, off));
        mt  = fmaxf(mt, __shfl_down(mt, off));
        sp2 += __shfl_down(sp2, off);
        st2 += __shfl_down(st2, off);
        spt += __shfl_down(spt, off);
    }
    int wave = t >> 6, lane = t & 63;
    if (lane == 0) {
        redm[wave][0] = sp2; redm[wave][1] = st2; redm[wave][2] = spt;
        redm[wave][3] = mp;  redm[wave][4] = mt;
    }
    __syncthreads();
    if (t == 0) {
        for (int w = 1; w < 4; ++w) {
            sp2 += redm[w][0];
            st2 += redm[w][1];
            spt += redm[w][2];
            mp = fmaxf(mp, redm[w][3]);
            mt = fmaxf(mt, redm[w][4]);
        }
        // plain stores -- NO atomics, NO fences (round-4 lesson: contended
        // same-line device atomics serialize at ~12ns each).
        partials[0 * B + b] = sp2;
        partials[1 * B + b] = st2;
        partials[2 * B + b] = spt;
        partials[3 * B + b] = mp;
        partials[4 * B + b] = mt;
    }
}

__global__ __launch_bounds__(1024)
void finalize_loss(const float* __restrict__ partials, float* __restrict__ out, int B) {
    __shared__ double reds[16][3];
    __shared__ float redx[16][2];
    const int t = threadIdx.x;
    double sp2 = 0.0, st2 = 0.0, spt = 0.0;
    float mp = 0.f, mt = 0.f;
    for (int i = t; i < B; i += 1024) {
        sp2 += (double)partials[0 * B + i];
        st2 += (double)partials[1 * B + i];
        spt += (double)partials[2 * B + i];
        mp = fmaxf(mp, partials[3 * B + i]);
        mt = fmaxf(mt, partials[4 * B + i]);
    }
    for (int off = 32; off > 0; off >>= 1) {
        sp2 += __shfl_down(sp2, off);
        st2 += __shfl_down(st2, off);
        spt += __shfl_down(spt, off);
        mp = fmaxf(mp, __shfl_down(mp, off));
        mt = fmaxf(mt, __shfl_down(mt, off));
    }
    int wave = t >> 6, lane = t & 63;
    if (lane == 0) {
        reds[wave][0] = sp2; reds[wave][1] = st2; reds[wave][2] = spt;
        redx[wave][0] = mp;  redx[wave][1] = mt;
    }
    __syncthreads();
    if (t == 0) {
        for (int w = 1; w < 16; ++w) {
            sp2 += reds[w][0];
            st2 += reds[w][1];
            spt += reds[w][2];
            mp = fmaxf(mp, redx[w][0]);
            mt = fmaxf(mt, redx[w][1]);
        }
        double Mp = (double)mp, Mt = (double)mt;
        double loss = (sp2 * (Mt / Mp) + st2 * (Mp / Mt) - 2.0 * spt) / sqrt(sp2 * st2);
        out[0] = (float)loss;
    }
}

extern "C" void kernel_launch(void* const* d_in, const int* in_sizes, int n_in,
                              void* d_out, int out_size, void* d_ws, size_t ws_size,
                              hipStream_t stream) {
    const float* output  = (const float*)d_in[0];
    const float* targets = (const float*)d_in[1];
    int B = in_sizes[0] / (NS * 3);
    float* partials = (float*)d_ws;     // 5*B floats

    loss_main<<<B, 256, 0, stream>>>(output, targets, partials, B);
    finalize_loss<<<1, 1024, 0, stream>>>(partials, (float*)d_out, B);
}